// Round 8
// baseline (221.428 us; speedup 1.0000x reference)
//
#include <hip/hip_runtime.h>

// NGP multiresolution hash-grid interpolation encoding.
// B=262144 points, DIM=3, L=16 levels, T=19 (2^19 entries/level), F=2.
//
// R12 = R11 (proven: gather 83us, total 182.2us) + brick-layout dense
// tables + level-7 densification.
//  - The kernel is L2-request-slot-bound at ~13 req/cyc/XCD (R11 ledger:
//    ~21M req / 83.5us). L1/MSHR merges same-64B-line accesses across
//    consecutive instructions of a wave -> spatial layout = fewer requests.
//  - Dense tables now 2x2x2 bricks (64B = one cacheline per cell
//    neighborhood): a point's 8 corner loads touch E[1.5^3]=3.375 lines
//    vs 4.5 (flat rows). Uniform 8x8B loads, no even/odd branch.
//  - Level 7 (res 80, 81^3 entries) joins the dense set (41^3 bricks,
//    4.4MB; slight L2 overspill to L3 is latency-only): 6 -> 3.375 req/pt.
//  - Request budget: dense 5x262k*3.375=4.42M + hash 8x262k*6=12.6M
//    (was 4.72M + 14.16M) => -1.6M req ~ -5us on gather.
// Unchanged: coarse LDS z-slabs (levels 0-2), hash path (levels 8-15),
// dwordx3 x-loads, level-major weighted XCD pinning, transpose kernel.

#define NB 262144
#define NL 16
#define TSIZE (1u << 19)
#define TMASK ((1u << 19) - 1u)
#define P1 2654435761u
#define P2 805459861u

#define NCL 3
#define CPTS 8192
#define COARSE_BLOCKS 256              // 32 (L0) + 64 (L1) + 160 (L2) slabs
#define CLDS_ENT (17 * 17 * 17)        // 4913 vf2 = 39304 B

// dense brick tables, levels 3..7: E = res+1 corners, BD = (E+1)/2 bricks
// per axis, brick = 8 vf2 = 64B. Offsets in vf2 units (brick-aligned).
#define E3 33
#define E4 41
#define E5 51
#define E6 65
#define E7 81
#define DB3 0
#define DB4 39304                      // + 17^3*8
#define DB5 113392                     // + 21^3*8
#define DB6 254000                     // + 26^3*8
#define DB7 541496                     // + 33^3*8
#define DENSE_B 541496                 // levels 3-6 (4,331,968 B)
#define DENSE_A 1092864                // levels 3-7 (8,742,912 B)

// fill units (even-x corner pairs) cumulative ends: BD*E*E per level
#define FC1 18513
#define FC2 53814
#define FC3 121440
#define FC4 260865
#define FTOT_A 529866

// fine: 13 levels x 512 chunks of 512 points, level-major chunk index
#define FINE_TOTAL 6656

typedef float vf2 __attribute__((ext_vector_type(2)));
typedef float vf4 __attribute__((ext_vector_type(4)));
typedef float vf3 __attribute__((ext_vector_type(3)));
typedef vf3 vf3a4 __attribute__((aligned(4), may_alias));

__constant__ float RES_C[NL] = {16.f, 20.f, 25.f, 32.f, 40.f, 50.f, 64.f, 80.f,
                                101.f, 128.f, 161.f, 203.f, 256.f, 322.f, 406.f, 512.f};

// weighted per-XCD fine-chunk boundaries (dense wt 3.7, hash wt 6.3)
__constant__ int XSPLIT_A[9] = {0, 1192, 2384, 3156, 3856, 4556, 5256, 5956, 6656};
__constant__ int XSPLIT_B[9] = {0, 1237, 2298, 3024, 3751, 4477, 5203, 5930, 6656};

__device__ __forceinline__ vf3 load_xyz(const float* __restrict__ p) {
  return *(const vf3a4*)p;  // one cached global_load_dwordx3
}

__device__ __forceinline__ void ngp_point_level(
    float px, float py, float pz, int l, const float* __restrict__ tables,
    float& o0, float& o1) {
  const float res = RES_C[l];
  const float sx = px * res, sy = py * res, sz = pz * res;
  const float fx = floorf(sx), fy = floorf(sy), fz = floorf(sz);
  const unsigned ix = (unsigned)fx, iy = (unsigned)fy, iz = (unsigned)fz;

  const unsigned hy0 = iy * P1, hy1 = hy0 + P1;
  const unsigned hz0 = iz * P2, hz1 = hz0 + P2;

  const float wx0 = 1.0f - fabsf(sx - fx);
  const float wx1 = 1.0f - fabsf(sx - (fx + 1.0f));
  const float wy0 = 1.0f - fabsf(sy - fy);
  const float wy1 = 1.0f - fabsf(sy - (fy + 1.0f));
  const float wz0 = 1.0f - fabsf(sz - fz);
  const float wz1 = 1.0f - fabsf(sz - (fz + 1.0f));

  const vf2* __restrict__ tbl2 = (const vf2*)tables + (size_t)l * TSIZE;
  const vf4* __restrict__ tbl4 = (const vf4*)tables + (size_t)l * (TSIZE / 2);

  unsigned hyz[4];
  hyz[0] = hy0 ^ hz0;
  hyz[1] = hy1 ^ hz0;
  hyz[2] = hy0 ^ hz1;
  hyz[3] = hy1 ^ hz1;

  vf2 g[8];  // g[v], v = xbit + 2*ybit + 4*zbit
  if ((ix & 1u) == 0u) {
#pragma unroll
    for (int p = 0; p < 4; ++p) {
      const unsigned i0 = (ix ^ hyz[p]) & TMASK;
      const vf4 q = tbl4[i0 >> 1];
      vf2 lo; lo.x = q.x; lo.y = q.y;
      vf2 hi; hi.x = q.z; hi.y = q.w;
      const bool x0_is_lo = (i0 & 1u) == 0u;
      g[2 * p + 0] = x0_is_lo ? lo : hi;
      g[2 * p + 1] = x0_is_lo ? hi : lo;
    }
  } else {
#pragma unroll
    for (int p = 0; p < 4; ++p) {
      const unsigned i0 = (ix ^ hyz[p]) & TMASK;
      const unsigned i1 = ((ix + 1u) ^ hyz[p]) & TMASK;
      g[2 * p + 0] = tbl2[i0];
      g[2 * p + 1] = tbl2[i1];
    }
  }

  o0 = 0.0f; o1 = 0.0f;
#pragma unroll
  for (int v = 0; v < 8; ++v) {
    const float w = ((v & 1) ? wx1 : wx0) * ((v & 2) ? wy1 : wy0) * ((v & 4) ? wz1 : wz0);
    o0 = fmaf(w, g[v].x, o0);
    o1 = fmaf(w, g[v].y, o1);
  }
}

// ---- dense-gather point (brick layout): 8 uniform 8B loads; same-line
// duplicates (x-pairs always; y/z on even parity) merge in L1/MSHR ----
template <int E, int DOFF_>
__device__ __forceinline__ void dense_point_brick(
    float px, float py, float pz, float res, const vf2* __restrict__ dense,
    float& o0, float& o1) {
  constexpr int BD = (E + 1) / 2;
  const float sx = px * res, sy = py * res, sz = pz * res;
  const float fx = floorf(sx), fy = floorf(sy), fz = floorf(sz);
  const int ix = (int)fx, iy = (int)fy, iz = (int)fz;

  const float wx0 = 1.0f - fabsf(sx - fx);
  const float wx1 = 1.0f - fabsf(sx - (fx + 1.0f));
  const float wy0 = 1.0f - fabsf(sy - fy);
  const float wy1 = 1.0f - fabsf(sy - (fy + 1.0f));
  const float wz0 = 1.0f - fabsf(sz - fz);
  const float wz1 = 1.0f - fabsf(sz - (fz + 1.0f));

  // per-axis (brick, offset) pairs for the two corners
  const int bx0 = ix >> 1, ox0 = ix & 1;
  const int bx1 = (ix + 1) >> 1, ox1 = (ix + 1) & 1;
  const int by0 = iy >> 1, oy0 = (iy & 1) * 2;
  const int by1 = (iy + 1) >> 1, oy1 = ((iy + 1) & 1) * 2;
  const int bz0 = iz >> 1, oz0 = (iz & 1) * 4;
  const int bz1 = (iz + 1) >> 1, oz1 = ((iz + 1) & 1) * 4;

  // brick-row bases (vf2 units)
  const int r00 = ((bz0 * BD + by0) * BD) * 8;
  const int r10 = ((bz0 * BD + by1) * BD) * 8;
  const int r01 = ((bz1 * BD + by0) * BD) * 8;
  const int r11 = ((bz1 * BD + by1) * BD) * 8;

  const vf2* __restrict__ d = dense + DOFF_;
  vf2 g[8];  // g[v], v = xbit + 2*ybit + 4*zbit
  g[0] = d[r00 + bx0 * 8 + oz0 + oy0 + ox0];
  g[1] = d[r00 + bx1 * 8 + oz0 + oy0 + ox1];
  g[2] = d[r10 + bx0 * 8 + oz0 + oy1 + ox0];
  g[3] = d[r10 + bx1 * 8 + oz0 + oy1 + ox1];
  g[4] = d[r01 + bx0 * 8 + oz1 + oy0 + ox0];
  g[5] = d[r01 + bx1 * 8 + oz1 + oy0 + ox1];
  g[6] = d[r11 + bx0 * 8 + oz1 + oy1 + ox0];
  g[7] = d[r11 + bx1 * 8 + oz1 + oy1 + ox1];

  o0 = 0.0f; o1 = 0.0f;
#pragma unroll
  for (int v = 0; v < 8; ++v) {
    const float w = ((v & 1) ? wx1 : wx0) * ((v & 2) ? wy1 : wy0) * ((v & 4) ? wz1 : wz0);
    o0 = fmaf(w, g[v].x, o0);
    o1 = fmaf(w, g[v].y, o1);
  }
}

// ---- coarse z-slab (levels 0-2), 512 threads ----
template <int E, int PLANES>
__device__ __forceinline__ void coarse_slab(
    const int lvl, const int zbase, const int c_lo, const int c_hi,
    const int cchunk, const float* __restrict__ x,
    const float* __restrict__ tables, vf2* __restrict__ ws,
    vf2* __restrict__ cache) {
  const int tid = threadIdx.x;
  const vf4* __restrict__ tbl4 = (const vf4*)tables + (size_t)lvl * (TSIZE / 2);

  constexpr int HE = (E + 1) / 2;
  constexpr int U = HE * E * PLANES;

  for (int u = tid; u < U; u += 512) {
    const int zp = u / (HE * E);
    const int rem = u - zp * (HE * E);
    const int iy = rem / HE;
    const int ixh = rem - iy * HE;
    const unsigned ix = 2u * (unsigned)ixh;
    const unsigned iz = (unsigned)(zbase + zp);
    const unsigned h0 = (ix ^ ((unsigned)iy * P1) ^ (iz * P2)) & TMASK;
    const vf4 q = tbl4[h0 >> 1];
    vf2 lo; lo.x = q.x; lo.y = q.y;
    vf2 hi; hi.x = q.z; hi.y = q.w;
    const bool x0_is_lo = (h0 & 1u) == 0u;
    const int d0 = (int)ix + E * iy + E * E * zp;
    cache[d0] = x0_is_lo ? lo : hi;
    if ((int)ix + 1 < E) cache[d0 + 1] = x0_is_lo ? hi : lo;
  }
  __syncthreads();

  const float res = RES_C[lvl];
  const int base = cchunk * CPTS;
#pragma unroll
  for (int k = 0; k < CPTS / 512; ++k) {
    const int b = base + k * 512 + tid;
    const vf3 pt = load_xyz(x + b * 3);
    const float px = pt.x, py = pt.y, pz = pt.z;

    const float sx = px * res, sy = py * res, sz = pz * res;
    const float fx = floorf(sx), fy = floorf(sy), fz = floorf(sz);
    const int ix = (int)fx, iy = (int)fy, iz = (int)fz;

    if (iz >= c_lo && iz <= c_hi) {
      const float wx0 = 1.0f - fabsf(sx - fx);
      const float wx1 = 1.0f - fabsf(sx - (fx + 1.0f));
      const float wy0 = 1.0f - fabsf(sy - fy);
      const float wy1 = 1.0f - fabsf(sy - (fy + 1.0f));
      const float wz0 = 1.0f - fabsf(sz - fz);
      const float wz1 = 1.0f - fabsf(sz - (fz + 1.0f));

      const int d = ix + E * iy + E * E * (iz - zbase);
      vf2 g[8];
      g[0] = cache[d];
      g[1] = cache[d + 1];
      g[2] = cache[d + E];
      g[3] = cache[d + E + 1];
      g[4] = cache[d + E * E];
      g[5] = cache[d + E * E + 1];
      g[6] = cache[d + E * E + E];
      g[7] = cache[d + E * E + E + 1];

      float o0 = 0.0f, o1 = 0.0f;
#pragma unroll
      for (int v = 0; v < 8; ++v) {
        const float w = ((v & 1) ? wx1 : wx0) * ((v & 2) ? wy1 : wy0) * ((v & 4) ? wz1 : wz0);
        o0 = fmaf(w, g[v].x, o0);
        o1 = fmaf(w, g[v].y, o1);
      }
      vf2 r; r.x = o0; r.y = o1;
      __builtin_nontemporal_store(r, ws + (size_t)lvl * NB + b);
    }
  }
}

// ---- kernel 0: fill brick dense tables (levels 3-6, optionally 7) ----
template <bool WITH_L7>
__global__ __launch_bounds__(512) void ngp_fill_dense(
    const float* __restrict__ tables, vf2* __restrict__ dense) {
  const int ftotal = WITH_L7 ? FTOT_A : FC4;
  for (int u = blockIdx.x * 512 + threadIdx.x; u < ftotal;
       u += gridDim.x * 512) {
    int lv, E, BD, doff, ubase;
    if (u < FC1)      { lv = 0; E = E3; BD = 17; doff = DB3; ubase = 0; }
    else if (u < FC2) { lv = 1; E = E4; BD = 21; doff = DB4; ubase = FC1; }
    else if (u < FC3) { lv = 2; E = E5; BD = 26; doff = DB5; ubase = FC2; }
    else if (u < FC4) { lv = 3; E = E6; BD = 33; doff = DB6; ubase = FC3; }
    else              { lv = 4; E = E7; BD = 41; doff = DB7; ubase = FC4; }
    const int ul = u - ubase;
    const int plane = BD * E;          // x-pairs per z-plane row group
    const int iz = ul / plane;
    const int rem = ul - iz * plane;
    const int iy = rem / BD;
    const int ixh = rem - iy * BD;
    const unsigned ix = 2u * (unsigned)ixh;
    const unsigned h0 = (ix ^ ((unsigned)iy * P1) ^ ((unsigned)iz * P2)) & TMASK;
    const vf4* __restrict__ tbl4 =
        (const vf4*)tables + (size_t)(NCL + lv) * (TSIZE / 2);
    const vf4 q = tbl4[h0 >> 1];
    vf2 lo; lo.x = q.x; lo.y = q.y;
    vf2 hi; hi.x = q.z; hi.y = q.w;
    const bool el = (h0 & 1u) == 0u;
    // brick address: ix even -> both corners in brick (ix>>1), dx=0,1
    const int brick = ((iz >> 1) * BD + (iy >> 1)) * BD + (int)(ix >> 1);
    const int ent = doff + brick * 8 + (iz & 1) * 4 + (iy & 1) * 2;
    vf4 w;
    if (el) { w.x = lo.x; w.y = lo.y; w.z = hi.x; w.w = hi.y; }
    else    { w.x = hi.x; w.y = hi.y; w.z = lo.x; w.w = lo.y; }
    *(vf4*)(dense + ent) = w;          // 16B aligned (ent even, doff 8-mult)
  }
}

// ---- kernel 1: gather. TIER 0: dense 3-7; TIER 1: dense 3-6 ----
template <int TIER>
__global__ __launch_bounds__(512, 8) void ngp_gather5(
    const float* __restrict__ x, const float* __restrict__ tables,
    vf2* __restrict__ ws) {
  __shared__ vf2 cache[CLDS_ENT];

  const int bid = blockIdx.x;
  if (bid < COARSE_BLOCKS) {
    if (bid < 32) {
      coarse_slab<17, 17>(0, 0, 0, 15, bid, x, tables, ws, cache);
    } else if (bid < 96) {
      const int u = bid - 32;
      const int half = u >> 5;
      coarse_slab<21, 11>(1, half * 10, half * 10, half * 10 + 9, u & 31,
                          x, tables, ws, cache);
    } else {
      const int u = bid - 96;
      const int s = u >> 5;
      coarse_slab<26, 6>(2, 5 * s, 5 * s, 5 * s + 4, u & 31,
                         x, tables, ws, cache);
    }
    return;
  }

  const int* xs = (TIER == 0) ? XSPLIT_A : XSPLIT_B;
  const int fid = bid - COARSE_BLOCKS;
  const int x8 = fid & 7;
  const int j = fid >> 3;
  const int c0 = xs[x8];
  if (j >= xs[x8 + 1] - c0) return;              // idle pad block
  const int c = c0 + j;                          // level-major chunk
  const int lvl = NCL + (c >> 9);                // 3..15
  const int b = (c & 511) * 512 + threadIdx.x;

  const vf3 pt = load_xyz(x + b * 3);
  const float px = pt.x, py = pt.y, pz = pt.z;

  const vf2* __restrict__ dense = ws + (size_t)NL * NB;
  const int dcut = (TIER == 0) ? 8 : 7;

  float o0, o1;
  if (lvl < dcut) {
    switch (lvl) {
      case 3:  dense_point_brick<E3, DB3>(px, py, pz, RES_C[3], dense, o0, o1); break;
      case 4:  dense_point_brick<E4, DB4>(px, py, pz, RES_C[4], dense, o0, o1); break;
      case 5:  dense_point_brick<E5, DB5>(px, py, pz, RES_C[5], dense, o0, o1); break;
      case 6:  dense_point_brick<E6, DB6>(px, py, pz, RES_C[6], dense, o0, o1); break;
      default: dense_point_brick<E7, DB7>(px, py, pz, RES_C[7], dense, o0, o1); break;
    }
  } else {
    ngp_point_level(px, py, pz, lvl, tables, o0, o1);
  }

  vf2 r; r.x = o0; r.y = o1;
  __builtin_nontemporal_store(r, ws + (size_t)lvl * NB + b);
}

// ---- fallback gather (R8 structure, no dense) ----
#define FINE_PER_XCD (FINE_TOTAL / 8)
__global__ __launch_bounds__(512, 8) void ngp_gather3(
    const float* __restrict__ x, const float* __restrict__ tables,
    vf2* __restrict__ ws) {
  __shared__ vf2 cache[CLDS_ENT];

  const int bid = blockIdx.x;
  if (bid < COARSE_BLOCKS) {
    if (bid < 32) {
      coarse_slab<17, 17>(0, 0, 0, 15, bid, x, tables, ws, cache);
    } else if (bid < 96) {
      const int u = bid - 32;
      const int half = u >> 5;
      coarse_slab<21, 11>(1, half * 10, half * 10, half * 10 + 9, u & 31,
                          x, tables, ws, cache);
    } else {
      const int u = bid - 96;
      const int s = u >> 5;
      coarse_slab<26, 6>(2, 5 * s, 5 * s, 5 * s + 4, u & 31,
                         x, tables, ws, cache);
    }
    return;
  }

  const int fid = bid - COARSE_BLOCKS;
  const int x8 = fid & 7;
  const int j = fid >> 3;
  const int g = x8 * FINE_PER_XCD + j;
  const int lvl = NCL + (g >> 9);
  const int b = (g & 511) * 512 + threadIdx.x;

  const vf3 pt = load_xyz(x + b * 3);

  float o0, o1;
  ngp_point_level(pt.x, pt.y, pt.z, lvl, tables, o0, o1);

  vf2 r; r.x = o0; r.y = o1;
  __builtin_nontemporal_store(r, ws + (size_t)lvl * NB + b);
}

// ---- phase 2: transpose ws[l][b] -> out[b][l*2+f], streaming ----
__global__ __launch_bounds__(256) void ngp_transpose_kernel(
    const vf2* __restrict__ ws, vf4* __restrict__ out4) {
  __shared__ vf2 tile[NL][257];
  const int t = threadIdx.x;
  const int p0 = blockIdx.x * 256;

#pragma unroll
  for (int l = 0; l < NL; ++l) {
    tile[l][t] = __builtin_nontemporal_load(ws + (size_t)l * NB + p0 + t);
  }
  __syncthreads();

#pragma unroll
  for (int k = 0; k < 8; ++k) {
    const int q = k * 256 + t;
    const int pq = q >> 3;
    const int wq = q & 7;
    const vf2 a = tile[2 * wq + 0][pq];
    const vf2 c = tile[2 * wq + 1][pq];
    vf4 v; v.x = a.x; v.y = a.y; v.z = c.x; v.w = c.y;
    __builtin_nontemporal_store(v, out4 + (size_t)p0 * 8 + q);
  }
}

// ---- fallback if workspace too small ----
__global__ __launch_bounds__(256) void ngp_fused_kernel(
    const float* __restrict__ x, const float* __restrict__ tables,
    float* __restrict__ out) {
  const int tid = blockIdx.x * blockDim.x + threadIdx.x;
  const int l = tid & (NL - 1);
  const int b = tid >> 4;
  const vf3 pt = load_xyz(x + b * 3);
  float o0, o1;
  ngp_point_level(pt.x, pt.y, pt.z, l, tables, o0, o1);
  float2 r = make_float2(o0, o1);
  ((float2*)out)[tid] = r;
}

extern "C" void kernel_launch(void* const* d_in, const int* in_sizes, int n_in,
                              void* d_out, int out_size, void* d_ws, size_t ws_size,
                              hipStream_t stream) {
  const float* x = (const float*)d_in[0];
  const float* tables = (const float*)d_in[1];
  float* out = (float*)d_out;

  const size_t ws_basic = (size_t)NL * NB * sizeof(vf2);        // 32 MB
  const size_t ws_tierB = ws_basic + (size_t)DENSE_B * 8;       // +4.33 MB
  const size_t ws_tierA = ws_basic + (size_t)DENSE_A * 8;       // +8.74 MB

  if (ws_size >= ws_tierA) {
    vf2* ws = (vf2*)d_ws;
    vf2* dense = ws + (size_t)NL * NB;
    ngp_fill_dense<true><<<1024, 512, 0, stream>>>(tables, dense);
    ngp_gather5<0><<<COARSE_BLOCKS + 8 * 1192, 512, 0, stream>>>(x, tables, ws);
    ngp_transpose_kernel<<<NB / 256, 256, 0, stream>>>(ws, (vf4*)out);
  } else if (ws_size >= ws_tierB) {
    vf2* ws = (vf2*)d_ws;
    vf2* dense = ws + (size_t)NL * NB;
    ngp_fill_dense<false><<<512, 512, 0, stream>>>(tables, dense);
    ngp_gather5<1><<<COARSE_BLOCKS + 8 * 1237, 512, 0, stream>>>(x, tables, ws);
    ngp_transpose_kernel<<<NB / 256, 256, 0, stream>>>(ws, (vf4*)out);
  } else if (ws_size >= ws_basic) {
    vf2* ws = (vf2*)d_ws;
    ngp_gather3<<<COARSE_BLOCKS + FINE_TOTAL, 512, 0, stream>>>(x, tables, ws);
    ngp_transpose_kernel<<<NB / 256, 256, 0, stream>>>(ws, (vf4*)out);
  } else {
    ngp_fused_kernel<<<NB * NL / 256, 256, 0, stream>>>(x, tables, out);
  }
}

// Round 9
// 181.380 us; speedup vs baseline: 1.2208x; 1.2208x over previous
//
#include <hip/hip_runtime.h>

// NGP multiresolution hash-grid interpolation encoding.
// B=262144 points, DIM=3, L=16 levels, T=19 (2^19 entries/level), F=2.
//
// R13 = exact revert to R11 (proven: gather 82-84us, total 182.2us).
// R12 post-mortem (brick layout, 120us gather): cross-instruction MSHR/L1
// merging does NOT happen on gfx950 — every load instruction issues its own
// L2 request per touched line. 8x8B brick loads = ~8 req/pt (vs flat's
// 4x16B unaligned = 4.5 req/pt), and the dense-cheap XSPLIT weighting
// inverted into a 2-XCD bottleneck (occupancy 50%, gather 120us).
// Request coalescing exists WITHIN one instruction only -> R11's single
// unaligned 16B load covering both x-corners is the minimal-request form.
// R11 structure (all proven):
//  - coarse LDS z-slabs, levels 0-2 (39.3KB LDS, 4 blocks/CU)
//  - dense re-indexed flat tables, levels 3-6: one 8B-aligned 16B load per
//    corner x-pair (4.5 req/pt), filled by a ~4us kernel
//  - hash path levels 7-15 (6 req/pt), level-major XCD pinning,
//    weighted split dense:hash = 3:4
//  - x coords: one cached dwordx3 per point
// Ledger: ~21M L2 requests / 13 req/cyc/XCD / 2.4GHz = 84us = measured.
// This is the request-slot roofline within ~5%.

#define NB 262144
#define NL 16
#define TSIZE (1u << 19)
#define TMASK ((1u << 19) - 1u)
#define P1 2654435761u
#define P2 805459861u

#define NCL 3
#define CPTS 8192
#define COARSE_BLOCKS 256              // 32 (L0) + 64 (L1) + 160 (L2) slabs
#define CLDS_ENT (17 * 17 * 17)        // 4913 vf2 = 39304 B

// dense levels 3..6: E = res+1, offsets in vf2 units (8B), 8-aligned
#define E3 33
#define E4 41
#define E5 51
#define E6 65
#define DOFF3 0
#define DOFF4 35944
#define DOFF5 104872
#define DOFF6 237528
#define DENSE_TOTAL 512160             // vf2 entries (4,097,280 B)

// fill units (even-x pairs), cumulative ends per level
#define FC1 18513
#define FC2 53814
#define FC3 121440
#define FTOTAL 260865

// fine: 13 levels x 512 chunks of 512 points, level-major chunk index
#define FINE_TOTAL 6656
#define FINE_MAXPX 1024                // max chunks per XCD (XSPLIT)
#define GRID_BLOCKS (COARSE_BLOCKS + 8 * FINE_MAXPX)  // 8448

typedef float vf2 __attribute__((ext_vector_type(2)));
typedef float vf4 __attribute__((ext_vector_type(4)));
typedef vf4 vf4a8 __attribute__((aligned(8), may_alias));
typedef float vf3 __attribute__((ext_vector_type(3)));
typedef vf3 vf3a4 __attribute__((aligned(4), may_alias));

__constant__ float RES_C[NL] = {16.f, 20.f, 25.f, 32.f, 40.f, 50.f, 64.f, 80.f,
                                101.f, 128.f, 161.f, 203.f, 256.f, 322.f, 406.f, 512.f};

// weighted per-XCD fine-chunk boundaries (dense=3, hash=4 per chunk)
__constant__ int XSPLIT[9] = {0, 1024, 2048, 2816, 3584, 4352, 5120, 5888, 6656};

// one cached 12B vector load (global_load_dwordx3)
__device__ __forceinline__ vf3 load_xyz(const float* __restrict__ p) {
  return *(const vf3a4*)p;
}

__device__ __forceinline__ void ngp_point_level(
    float px, float py, float pz, int l, const float* __restrict__ tables,
    float& o0, float& o1) {
  const float res = RES_C[l];
  const float sx = px * res, sy = py * res, sz = pz * res;
  const float fx = floorf(sx), fy = floorf(sy), fz = floorf(sz);
  const unsigned ix = (unsigned)fx, iy = (unsigned)fy, iz = (unsigned)fz;

  const unsigned hy0 = iy * P1, hy1 = hy0 + P1;
  const unsigned hz0 = iz * P2, hz1 = hz0 + P2;

  const float wx0 = 1.0f - fabsf(sx - fx);
  const float wx1 = 1.0f - fabsf(sx - (fx + 1.0f));
  const float wy0 = 1.0f - fabsf(sy - fy);
  const float wy1 = 1.0f - fabsf(sy - (fy + 1.0f));
  const float wz0 = 1.0f - fabsf(sz - fz);
  const float wz1 = 1.0f - fabsf(sz - (fz + 1.0f));

  const vf2* __restrict__ tbl2 = (const vf2*)tables + (size_t)l * TSIZE;
  const vf4* __restrict__ tbl4 = (const vf4*)tables + (size_t)l * (TSIZE / 2);

  unsigned hyz[4];
  hyz[0] = hy0 ^ hz0;
  hyz[1] = hy1 ^ hz0;
  hyz[2] = hy0 ^ hz1;
  hyz[3] = hy1 ^ hz1;

  vf2 g[8];  // g[v], v = xbit + 2*ybit + 4*zbit
  if ((ix & 1u) == 0u) {
#pragma unroll
    for (int p = 0; p < 4; ++p) {
      const unsigned i0 = (ix ^ hyz[p]) & TMASK;
      const vf4 q = tbl4[i0 >> 1];
      vf2 lo; lo.x = q.x; lo.y = q.y;
      vf2 hi; hi.x = q.z; hi.y = q.w;
      const bool x0_is_lo = (i0 & 1u) == 0u;
      g[2 * p + 0] = x0_is_lo ? lo : hi;
      g[2 * p + 1] = x0_is_lo ? hi : lo;
    }
  } else {
#pragma unroll
    for (int p = 0; p < 4; ++p) {
      const unsigned i0 = (ix ^ hyz[p]) & TMASK;
      const unsigned i1 = ((ix + 1u) ^ hyz[p]) & TMASK;
      g[2 * p + 0] = tbl2[i0];
      g[2 * p + 1] = tbl2[i1];
    }
  }

  o0 = 0.0f; o1 = 0.0f;
#pragma unroll
  for (int v = 0; v < 8; ++v) {
    const float w = ((v & 1) ? wx1 : wx0) * ((v & 2) ? wy1 : wy0) * ((v & 4) ? wz1 : wz0);
    o0 = fmaf(w, g[v].x, o0);
    o1 = fmaf(w, g[v].y, o1);
  }
}

// ---- dense-gather point (levels 3-6): coordinate-indexed table ----
template <int E, int DOFF_>
__device__ __forceinline__ void dense_point(
    float px, float py, float pz, float res, const vf2* __restrict__ dense,
    float& o0, float& o1) {
  const float sx = px * res, sy = py * res, sz = pz * res;
  const float fx = floorf(sx), fy = floorf(sy), fz = floorf(sz);
  const int ix = (int)fx, iy = (int)fy, iz = (int)fz;

  const float wx0 = 1.0f - fabsf(sx - fx);
  const float wx1 = 1.0f - fabsf(sx - (fx + 1.0f));
  const float wy0 = 1.0f - fabsf(sy - fy);
  const float wy1 = 1.0f - fabsf(sy - (fy + 1.0f));
  const float wz0 = 1.0f - fabsf(sz - fz);
  const float wz1 = 1.0f - fabsf(sz - (fz + 1.0f));

  const vf2* __restrict__ dp = dense + DOFF_ + ix + E * iy + E * E * iz;

  vf2 g[8];
#pragma unroll
  for (int p = 0; p < 4; ++p) {
    const int row = ((p & 1) ? E : 0) + ((p & 2) ? E * E : 0);
    const vf4 q = *(const vf4a8*)(dp + row);  // one 16B load, both x corners
    g[2 * p + 0].x = q.x; g[2 * p + 0].y = q.y;
    g[2 * p + 1].x = q.z; g[2 * p + 1].y = q.w;
  }

  o0 = 0.0f; o1 = 0.0f;
#pragma unroll
  for (int v = 0; v < 8; ++v) {
    const float w = ((v & 1) ? wx1 : wx0) * ((v & 2) ? wy1 : wy0) * ((v & 4) ? wz1 : wz0);
    o0 = fmaf(w, g[v].x, o0);
    o1 = fmaf(w, g[v].y, o1);
  }
}

// ---- coarse z-slab (levels 0-2), 512 threads ----
template <int E, int PLANES>
__device__ __forceinline__ void coarse_slab(
    const int lvl, const int zbase, const int c_lo, const int c_hi,
    const int cchunk, const float* __restrict__ x,
    const float* __restrict__ tables, vf2* __restrict__ ws,
    vf2* __restrict__ cache) {
  const int tid = threadIdx.x;
  const vf4* __restrict__ tbl4 = (const vf4*)tables + (size_t)lvl * (TSIZE / 2);

  constexpr int HE = (E + 1) / 2;
  constexpr int U = HE * E * PLANES;

  for (int u = tid; u < U; u += 512) {
    const int zp = u / (HE * E);
    const int rem = u - zp * (HE * E);
    const int iy = rem / HE;
    const int ixh = rem - iy * HE;
    const unsigned ix = 2u * (unsigned)ixh;
    const unsigned iz = (unsigned)(zbase + zp);
    const unsigned h0 = (ix ^ ((unsigned)iy * P1) ^ (iz * P2)) & TMASK;
    const vf4 q = tbl4[h0 >> 1];
    vf2 lo; lo.x = q.x; lo.y = q.y;
    vf2 hi; hi.x = q.z; hi.y = q.w;
    const bool x0_is_lo = (h0 & 1u) == 0u;
    const int d0 = (int)ix + E * iy + E * E * zp;
    cache[d0] = x0_is_lo ? lo : hi;
    if ((int)ix + 1 < E) cache[d0 + 1] = x0_is_lo ? hi : lo;
  }
  __syncthreads();

  const float res = RES_C[lvl];
  const int base = cchunk * CPTS;
#pragma unroll
  for (int k = 0; k < CPTS / 512; ++k) {
    const int b = base + k * 512 + tid;
    const vf3 pt = load_xyz(x + b * 3);
    const float px = pt.x, py = pt.y, pz = pt.z;

    const float sx = px * res, sy = py * res, sz = pz * res;
    const float fx = floorf(sx), fy = floorf(sy), fz = floorf(sz);
    const int ix = (int)fx, iy = (int)fy, iz = (int)fz;

    if (iz >= c_lo && iz <= c_hi) {
      const float wx0 = 1.0f - fabsf(sx - fx);
      const float wx1 = 1.0f - fabsf(sx - (fx + 1.0f));
      const float wy0 = 1.0f - fabsf(sy - fy);
      const float wy1 = 1.0f - fabsf(sy - (fy + 1.0f));
      const float wz0 = 1.0f - fabsf(sz - fz);
      const float wz1 = 1.0f - fabsf(sz - (fz + 1.0f));

      const int d = ix + E * iy + E * E * (iz - zbase);
      vf2 g[8];
      g[0] = cache[d];
      g[1] = cache[d + 1];
      g[2] = cache[d + E];
      g[3] = cache[d + E + 1];
      g[4] = cache[d + E * E];
      g[5] = cache[d + E * E + 1];
      g[6] = cache[d + E * E + E];
      g[7] = cache[d + E * E + E + 1];

      float o0 = 0.0f, o1 = 0.0f;
#pragma unroll
      for (int v = 0; v < 8; ++v) {
        const float w = ((v & 1) ? wx1 : wx0) * ((v & 2) ? wy1 : wy0) * ((v & 4) ? wz1 : wz0);
        o0 = fmaf(w, g[v].x, o0);
        o1 = fmaf(w, g[v].y, o1);
      }
      vf2 r; r.x = o0; r.y = o1;
      __builtin_nontemporal_store(r, ws + (size_t)lvl * NB + b);
    }
  }
}

// ---- kernel 0: fill dense tables for levels 3-6 ----
__global__ __launch_bounds__(512) void ngp_fill_dense(
    const float* __restrict__ tables, vf2* __restrict__ dense) {
  for (int u = blockIdx.x * 512 + threadIdx.x; u < FTOTAL;
       u += gridDim.x * 512) {
    int lv, E, doff, ubase;
    if (u < FC1)      { lv = 0; E = E3; doff = DOFF3; ubase = 0; }
    else if (u < FC2) { lv = 1; E = E4; doff = DOFF4; ubase = FC1; }
    else if (u < FC3) { lv = 2; E = E5; doff = DOFF5; ubase = FC2; }
    else              { lv = 3; E = E6; doff = DOFF6; ubase = FC3; }
    const int ul = u - ubase;
    const int HE = (E + 1) >> 1;
    const int plane = HE * E;
    const int iz = ul / plane;
    const int rem = ul - iz * plane;
    const int iy = rem / HE;
    const int ixh = rem - iy * HE;
    const unsigned ix = 2u * (unsigned)ixh;
    const unsigned h0 = (ix ^ ((unsigned)iy * P1) ^ ((unsigned)iz * P2)) & TMASK;
    const vf4* __restrict__ tbl4 =
        (const vf4*)tables + (size_t)(NCL + lv) * (TSIZE / 2);
    const vf4 q = tbl4[h0 >> 1];
    vf2 lo; lo.x = q.x; lo.y = q.y;
    vf2 hi; hi.x = q.z; hi.y = q.w;
    const bool el = (h0 & 1u) == 0u;
    const int d0 = doff + (int)ix + E * iy + E * E * iz;
    dense[d0] = el ? lo : hi;
    if ((int)ix + 1 < E) dense[d0 + 1] = el ? hi : lo;
  }
}

// ---- kernel 1: gather (coarse slabs; dense levels 3-6; hash 7-15) ----
__global__ __launch_bounds__(512, 8) void ngp_gather4(
    const float* __restrict__ x, const float* __restrict__ tables,
    vf2* __restrict__ ws) {
  __shared__ vf2 cache[CLDS_ENT];

  const int bid = blockIdx.x;
  if (bid < COARSE_BLOCKS) {
    if (bid < 32) {
      coarse_slab<17, 17>(0, 0, 0, 15, bid, x, tables, ws, cache);
    } else if (bid < 96) {
      const int u = bid - 32;
      const int half = u >> 5;
      coarse_slab<21, 11>(1, half * 10, half * 10, half * 10 + 9, u & 31,
                          x, tables, ws, cache);
    } else {
      const int u = bid - 96;
      const int s = u >> 5;
      coarse_slab<26, 6>(2, 5 * s, 5 * s, 5 * s + 4, u & 31,
                         x, tables, ws, cache);
    }
    return;
  }

  const int fid = bid - COARSE_BLOCKS;           // 0..8191
  const int x8 = fid & 7;
  const int j = fid >> 3;                        // 0..1023
  const int c0 = XSPLIT[x8];
  if (j >= XSPLIT[x8 + 1] - c0) return;          // idle pad block
  const int c = c0 + j;                          // level-major chunk
  const int lvl = NCL + (c >> 9);                // 3..15
  const int b = (c & 511) * 512 + threadIdx.x;

  const vf3 pt = load_xyz(x + b * 3);
  const float px = pt.x, py = pt.y, pz = pt.z;

  const vf2* __restrict__ dense = ws + (size_t)NL * NB;

  float o0, o1;
  if (lvl < 7) {
    switch (lvl) {
      case 3:  dense_point<E3, DOFF3>(px, py, pz, RES_C[3], dense, o0, o1); break;
      case 4:  dense_point<E4, DOFF4>(px, py, pz, RES_C[4], dense, o0, o1); break;
      case 5:  dense_point<E5, DOFF5>(px, py, pz, RES_C[5], dense, o0, o1); break;
      default: dense_point<E6, DOFF6>(px, py, pz, RES_C[6], dense, o0, o1); break;
    }
  } else {
    ngp_point_level(px, py, pz, lvl, tables, o0, o1);
  }

  vf2 r; r.x = o0; r.y = o1;
  __builtin_nontemporal_store(r, ws + (size_t)lvl * NB + b);
}

// ---- fallback gather (R8 structure) for smaller workspace ----
#define FINE_PER_XCD (FINE_TOTAL / 8)
__global__ __launch_bounds__(512, 8) void ngp_gather3(
    const float* __restrict__ x, const float* __restrict__ tables,
    vf2* __restrict__ ws) {
  __shared__ vf2 cache[CLDS_ENT];

  const int bid = blockIdx.x;
  if (bid < COARSE_BLOCKS) {
    if (bid < 32) {
      coarse_slab<17, 17>(0, 0, 0, 15, bid, x, tables, ws, cache);
    } else if (bid < 96) {
      const int u = bid - 32;
      const int half = u >> 5;
      coarse_slab<21, 11>(1, half * 10, half * 10, half * 10 + 9, u & 31,
                          x, tables, ws, cache);
    } else {
      const int u = bid - 96;
      const int s = u >> 5;
      coarse_slab<26, 6>(2, 5 * s, 5 * s, 5 * s + 4, u & 31,
                         x, tables, ws, cache);
    }
    return;
  }

  const int fid = bid - COARSE_BLOCKS;
  const int x8 = fid & 7;
  const int j = fid >> 3;
  const int g = x8 * FINE_PER_XCD + j;
  const int lvl = NCL + (g >> 9);
  const int b = (g & 511) * 512 + threadIdx.x;

  const vf3 pt = load_xyz(x + b * 3);

  float o0, o1;
  ngp_point_level(pt.x, pt.y, pt.z, lvl, tables, o0, o1);

  vf2 r; r.x = o0; r.y = o1;
  __builtin_nontemporal_store(r, ws + (size_t)lvl * NB + b);
}

// ---- phase 2: transpose ws[l][b] -> out[b][l*2+f], streaming ----
__global__ __launch_bounds__(256) void ngp_transpose_kernel(
    const vf2* __restrict__ ws, vf4* __restrict__ out4) {
  __shared__ vf2 tile[NL][257];
  const int t = threadIdx.x;
  const int p0 = blockIdx.x * 256;

#pragma unroll
  for (int l = 0; l < NL; ++l) {
    tile[l][t] = __builtin_nontemporal_load(ws + (size_t)l * NB + p0 + t);
  }
  __syncthreads();

#pragma unroll
  for (int k = 0; k < 8; ++k) {
    const int q = k * 256 + t;
    const int pq = q >> 3;
    const int wq = q & 7;
    const vf2 a = tile[2 * wq + 0][pq];
    const vf2 c = tile[2 * wq + 1][pq];
    vf4 v; v.x = a.x; v.y = a.y; v.z = c.x; v.w = c.y;
    __builtin_nontemporal_store(v, out4 + (size_t)p0 * 8 + q);
  }
}

// ---- fallback if workspace too small ----
__global__ __launch_bounds__(256) void ngp_fused_kernel(
    const float* __restrict__ x, const float* __restrict__ tables,
    float* __restrict__ out) {
  const int tid = blockIdx.x * blockDim.x + threadIdx.x;
  const int l = tid & (NL - 1);
  const int b = tid >> 4;
  const vf3 pt = load_xyz(x + b * 3);
  float o0, o1;
  ngp_point_level(pt.x, pt.y, pt.z, l, tables, o0, o1);
  float2 r = make_float2(o0, o1);
  ((float2*)out)[tid] = r;
}

extern "C" void kernel_launch(void* const* d_in, const int* in_sizes, int n_in,
                              void* d_out, int out_size, void* d_ws, size_t ws_size,
                              hipStream_t stream) {
  const float* x = (const float*)d_in[0];
  const float* tables = (const float*)d_in[1];
  float* out = (float*)d_out;

  const size_t ws_basic = (size_t)NL * NB * sizeof(vf2);           // 32 MB
  const size_t ws_dense = ws_basic + (size_t)DENSE_TOTAL * 8;      // +4.1 MB

  if (ws_size >= ws_dense) {
    vf2* ws = (vf2*)d_ws;
    vf2* dense = ws + (size_t)NL * NB;
    ngp_fill_dense<<<512, 512, 0, stream>>>(tables, dense);
    ngp_gather4<<<GRID_BLOCKS, 512, 0, stream>>>(x, tables, ws);
    ngp_transpose_kernel<<<NB / 256, 256, 0, stream>>>(ws, (vf4*)out);
  } else if (ws_size >= ws_basic) {
    vf2* ws = (vf2*)d_ws;
    ngp_gather3<<<COARSE_BLOCKS + FINE_TOTAL, 512, 0, stream>>>(x, tables, ws);
    ngp_transpose_kernel<<<NB / 256, 256, 0, stream>>>(ws, (vf4*)out);
  } else {
    ngp_fused_kernel<<<NB * NL / 256, 256, 0, stream>>>(x, tables, out);
  }
}